// Round 5
// baseline (326.599 us; speedup 1.0000x reference)
//
#include <hip/hip_runtime.h>

#define T_SEQ 2048
#define DHEAD 128
#define NBH 16
#define SCALE 0.08838834764831845f

typedef unsigned short u16;
typedef unsigned int u32;
typedef u16 u16x4 __attribute__((ext_vector_type(4)));
typedef u16 u16x8 __attribute__((ext_vector_type(8)));
typedef u32 u32x2 __attribute__((ext_vector_type(2)));
typedef short s16x4 __attribute__((ext_vector_type(4)));
typedef __bf16 bf16x8 __attribute__((ext_vector_type(8)));
typedef float f32x4 __attribute__((ext_vector_type(4)));

__device__ __forceinline__ u16 f2bfu(float x) {
  union { float f; unsigned u; } c; c.f = x;
  unsigned u = c.u;
  u = u + 0x7FFFu + ((u >> 16) & 1u);   // RNE
  return (u16)(u >> 16);
}

__device__ __forceinline__ bf16x8 ldsFrag(const u16* p) {
  u16x8 t = *(const u16x8*)p;
  return __builtin_bit_cast(bf16x8, t);
}

__device__ __forceinline__ f32x4 mfma16x16x16bf16(s16x4 a, s16x4 b, f32x4 c) {
#if __has_builtin(__builtin_amdgcn_mfma_f32_16x16x16bf16_1k)
  return __builtin_amdgcn_mfma_f32_16x16x16bf16_1k(a, b, c, 0, 0, 0);
#else
  asm("v_mfma_f32_16x16x16_bf16 %0, %1, %2, %0" : "+v"(c) : "v"(a), "v"(b));
  return c;
#endif
}

__device__ __forceinline__ void gld_lds16(const void* g, void* l) {
  __builtin_amdgcn_global_load_lds(
      (__attribute__((address_space(1))) const unsigned int*)g,
      (__attribute__((address_space(3))) unsigned int*)l, 16, 0, 0);
}

// ---------------------------------------------------------------------------
// Gate scan: fc=cumsum(logsigmoid(f)); a=i-fc; c=cummax(a).
// ---------------------------------------------------------------------------
__global__ __launch_bounds__(1024) void gate_scan_kernel(
    const float* __restrict__ ig, const float* __restrict__ fg,
    float* __restrict__ a_out, float* __restrict__ c_out,
    float* __restrict__ fc_out)
{
  const int bh = blockIdx.x, tid = threadIdx.x;
  const int w = tid >> 6, lane = tid & 63;
  const int base = bh * T_SEQ + tid * 2;
  __shared__ float wsum[16];
  __shared__ float wmax[16];

  const float x0 = fg[base], x1 = fg[base + 1];
  const float ls0 = fminf(x0, 0.f) - log1pf(expf(-fabsf(x0)));
  const float ls1 = fminf(x1, 0.f) - log1pf(expf(-fabsf(x1)));
  const float s = ls0 + ls1;

  float sc = s;
#pragma unroll
  for (int off = 1; off < 64; off <<= 1) {
    const float t = __shfl_up(sc, off, 64);
    if (lane >= off) sc += t;
  }
  if (lane == 63) wsum[w] = sc;
  __syncthreads();
  float wo = 0.f;
#pragma unroll
  for (int i = 0; i < 15; ++i) if (i < w) wo += wsum[i];
  const float excl = wo + (sc - s);
  const float fc0 = excl + ls0;
  const float fc1 = excl + ls0 + ls1;
  fc_out[base] = fc0; fc_out[base + 1] = fc1;
  const float a0 = ig[base] - fc0;
  const float a1 = ig[base + 1] - fc1;
  a_out[base] = a0; a_out[base + 1] = a1;

  const float m = fmaxf(a0, a1);
  float mc = m;
#pragma unroll
  for (int off = 1; off < 64; off <<= 1) {
    const float t = __shfl_up(mc, off, 64);
    if (lane >= off) mc = fmaxf(mc, t);
  }
  if (lane == 63) wmax[w] = mc;
  __syncthreads();
  float wmo = -INFINITY;
#pragma unroll
  for (int i = 0; i < 15; ++i) if (i < w) wmo = fmaxf(wmo, wmax[i]);
  const float prev = __shfl_up(mc, 1, 64);
  float exclm = (lane > 0) ? prev : -INFINITY;
  exclm = fmaxf(exclm, wmo);
  c_out[base] = fmaxf(exclm, a0);
  c_out[base + 1] = fmaxf(exclm, m);
}

// ---------------------------------------------------------------------------
// Fused pre-pass: K_hat = K*exp(a-c_end) fp32->bf16; V -> bf16 Vt transposed.
// ---------------------------------------------------------------------------
__global__ __launch_bounds__(256) void cvt_kv_kernel(
    const float* __restrict__ kk, const float* __restrict__ v,
    const float* __restrict__ ag, const float* __restrict__ cg,
    u16* __restrict__ kbf, u16* __restrict__ vt)
{
  const int bh = blockIdx.y, kt = blockIdx.x, tid = threadIdx.x;
  // ---- K part ----
  {
    const int r = tid >> 2;                 // 0..63
    const int c0 = (tid & 3) * 32;
    const int row = kt * 64 + r;
    const float sc = __expf(ag[bh * T_SEQ + row] - cg[bh * T_SEQ + (row | 63)]);
    const float* sp = kk + ((size_t)bh * T_SEQ + row) * DHEAD + c0;
    u16* dp = kbf + ((size_t)bh * T_SEQ + row) * DHEAD + c0;
#pragma unroll
    for (int j = 0; j < 8; ++j) {
      const float4 x = *(const float4*)(sp + j * 4);
      u16x4 pq;
      pq[0] = f2bfu(x.x * sc); pq[1] = f2bfu(x.y * sc);
      pq[2] = f2bfu(x.z * sc); pq[3] = f2bfu(x.w * sc);
      *(u16x4*)(dp + j * 4) = pq;
    }
  }
  // ---- V transpose part ----
  __shared__ __align__(16) u16 L[128 * 72];
  const int n0 = (tid & 31) * 4, k0 = (tid >> 5) * 8;
  const float* vp = v + ((size_t)bh * T_SEQ + kt * 64 + k0) * DHEAD + n0;
  u16 tv[4][8];
#pragma unroll
  for (int rr = 0; rr < 8; ++rr) {
    const float4 x = *(const float4*)(vp + rr * DHEAD);
    tv[0][rr] = f2bfu(x.x); tv[1][rr] = f2bfu(x.y);
    tv[2][rr] = f2bfu(x.z); tv[3][rr] = f2bfu(x.w);
  }
#pragma unroll
  for (int j = 0; j < 4; ++j) {
    u16x8 pq;
#pragma unroll
    for (int rr = 0; rr < 8; ++rr) pq[rr] = tv[j][rr];
    *(u16x8*)(&L[(n0 + j) * 72 + k0]) = pq;
  }
  __syncthreads();
  const int row = tid >> 1, s0 = (tid & 1) * 32;
  u16* op = vt + ((size_t)bh * DHEAD + row) * T_SEQ + kt * 64 + s0;
#pragma unroll
  for (int i = 0; i < 4; ++i)
    *(u16x8*)(op + i * 8) = *(const u16x8*)(&L[row * 72 + s0 + i * 8]);
}

// ---------------------------------------------------------------------------
// Main flash mLSTM.  256 blocks x 512 thr (8 waves, R0's proven 256-reg
// footprint: qf[16]=64 VGPR + oa[8][4]=128 AGPR, no spill at (512,1)).
// UNIFORM 17-window schedule, TWO STAGES PER WINDOW ON DIFFERENT WAVES:
//   block (bh,p): tile A=31-p (stages 0..31-p) then tile B=p (0..p);
//   ceil(nA/2)+ceil(nB/2) == 17 for every p.
// Wave = kg(4 key-groups of 16) x sg(2): wave (kg,sg) computes stage 2g+sg
// over 16 keys x ALL 64 rows.  Each SIMD hosts one sg=0 and one sg=1 wave
// -> two INDEPENDENT per-stage dependency chains overlap per SIMD (the
// round-0..4 invariant: ~3900 cyc per stage-chain; R4 proved same-wave
// serialization doubles it; different-wave should halve wall time).
// LDS economics = R0's optimum: K-redundancy 1, V-redundancy 1
// (64KB reads/window).  4 staging slots x 32KB, pair ping-pong.
// Epilogue: 8 partials (kg x sg) combined via mt-rotation rounds (all 8
// waves busy every round) in osh overlaid on the dead slot-pair.
// XCD swizzle: 2 bh per XCD so same-bh K/V re-reads hit one L2.
// ---------------------------------------------------------------------------
template <bool FAST>
__global__ __launch_bounds__(512, 1) void mlstm_fwd_kernel(
    const float* __restrict__ qg, const float* __restrict__ kxg,
    const float* __restrict__ vg,
    const u16* __restrict__ kbf, const u16* __restrict__ vtbf,
    const float* __restrict__ ag, const float* __restrict__ cg,
    const float* __restrict__ fcg, float* __restrict__ out)
{
  const int bx = (int)blockIdx.x;
  const int bh = ((bx & 7) << 1) | ((bx >> 3) & 1);   // 2 bh per XCD
  const int p  = bx >> 4;
  const int tid = (int)threadIdx.x;
  const int w = tid >> 6, lane = tid & 63;
  const int quad = lane >> 4, l16 = lane & 15;
  const int kg = w & 3, sg = w >> 2;

  const int qtA = 31 - p, qtB = p;
  const int nA = qtA + 1, nB = qtB + 1;   // nA in 17..32, nB in 1..16

  // LDS: 4 staging slots x 32KB (K 16K + V 16K each) = 128KB.
  // Epilogue osh(64x132 f32) + rsh(8x64) + ish(64) overlay the dead pair.
  __shared__ __align__(16) unsigned char SM[131072];
  u16* Kst = (u16*)SM;

  const size_t hoff = (size_t)bh * T_SEQ * DHEAD;
  const int goff = bh * T_SEQ;

  // Q -> B-frags qf[nt*4+kc]: B[k=quad*8+j][n=l16], row = qt*64+nt*16+l16
  bf16x8 qf[16];
  auto loadQ = [&](int lqt) {
    const float* qp = qg + hoff + (size_t)(lqt * 64) * DHEAD;
#pragma unroll
    for (int nt = 0; nt < 4; ++nt) {
      const float* qr = qp + (size_t)(nt * 16 + l16) * DHEAD + quad * 8;
#pragma unroll
      for (int kc = 0; kc < 4; ++kc) {
        const float4 x0 = *(const float4*)(qr + kc * 32);
        const float4 x1 = *(const float4*)(qr + kc * 32 + 4);
        u16x8 t;
        t[0] = f2bfu(x0.x); t[1] = f2bfu(x0.y); t[2] = f2bfu(x0.z); t[3] = f2bfu(x0.w);
        t[4] = f2bfu(x1.x); t[5] = f2bfu(x1.y); t[6] = f2bfu(x1.z); t[7] = f2bfu(x1.w);
        qf[nt * 4 + kc] = __builtin_bit_cast(bf16x8, t);
      }
    }
  };

  f32x4 oa[8][4];                 // O^T partial: 8 vd-tiles x 4 row-tiles
  float rsacc[4];
  auto zeroAcc = [&]() {
#pragma unroll
    for (int mt = 0; mt < 8; ++mt)
#pragma unroll
      for (int nt = 0; nt < 4; ++nt) oa[mt][nt] = (f32x4){0.f, 0.f, 0.f, 0.f};
#pragma unroll
    for (int nt = 0; nt < 4; ++nt) rsacc[nt] = 0.f;
  };
  zeroAcc();

  // ---- staging invariants: thread handles chunks B0=tid, B1=tid+512 ----
  const int B0 = tid, B1 = tid + 512;
  const int k0key = B0 >> 4, k0db = (B0 & 15) ^ (k0key & 7);
  const int k1key = B1 >> 4, k1db = (B1 & 15) ^ (k1key & 7);
  const int v0n = B0 >> 3, v0k = (B0 & 7) ^ (v0n & 7);
  const int v1n = B1 >> 3, v1k = (B1 & 7) ^ (v1n & 7);
  const u16* kG = kbf + (size_t)goff * DHEAD;
  const u16* vG = vtbf + (size_t)bh * DHEAD * T_SEQ;

  // stage key-tile st into slot (K 16KB + V 16KB); 4 gld16 per thread
  auto stage = [&](int st, int slot) {
    u16* KbL = Kst + slot * 16384;
    u16* VbL = KbL + 8192;
    if (FAST) {
      const u16* ks = kG + (size_t)st * (64 * DHEAD);
      const u16* vs = vG + st * 64;
      gld_lds16(ks + k0key * DHEAD + k0db * 8, KbL + w * 512);
      gld_lds16(ks + k1key * DHEAD + k1db * 8, KbL + 4096 + w * 512);
      gld_lds16(vs + (size_t)v0n * T_SEQ + v0k * 8, VbL + w * 512);
      gld_lds16(vs + (size_t)v1n * T_SEQ + v1k * 8, VbL + 4096 + w * 512);
    } else {
      const float ct = cg[goff + st * 64 + 63];
      const float* kp = kxg + hoff + (size_t)(st * 64) * DHEAD;
      const float* vp = vg + hoff + (size_t)(st * 64) * DHEAD;
#pragma unroll
      for (int j = 0; j < 2; ++j) {
        const int key = j ? k1key : k0key, db = j ? k1db : k0db;
        const int Bc = j ? B1 : B0;
        const float scv = __expf(ag[goff + st * 64 + key] - ct);
        const float4 x0 = *(const float4*)(kp + (size_t)key * DHEAD + db * 8);
        const float4 x1 = *(const float4*)(kp + (size_t)key * DHEAD + db * 8 + 4);
        u16x8 pk;
        pk[0] = f2bfu(x0.x * scv); pk[1] = f2bfu(x0.y * scv);
        pk[2] = f2bfu(x0.z * scv); pk[3] = f2bfu(x0.w * scv);
        pk[4] = f2bfu(x1.x * scv); pk[5] = f2bfu(x1.y * scv);
        pk[6] = f2bfu(x1.z * scv); pk[7] = f2bfu(x1.w * scv);
        *(u16x8*)(KbL + Bc * 8) = pk;
        const int n = j ? v1n : v0n, kb = j ? v1k : v0k;
        u16x8 pw;
#pragma unroll
        for (int rr = 0; rr < 8; ++rr)
          pw[rr] = f2bfu(vp[(size_t)(kb * 8 + rr) * DHEAD + n]);
        *(u16x8*)(VbL + Bc * 8) = pw;
      }
    }
  };

  const int keyA = kg * 16 + l16;         // A-frag key row (QK)
  const int ksw  = l16 & 7;
  // vd&7 == l16&7 for all mt -> V swizzle is mt-invariant:
  const int vbase = l16 * 64 + (((kg * 2 + (quad >> 1)) ^ (l16 & 7)) * 8) + (quad & 1) * 4;

  auto computeStage = [&](int cqt, int st, int slot, float ccmax) {
    const u16* KbL = Kst + slot * 16384;
    const u16* VbL = KbL + 8192;

    // ---- S^T = K_hat Q^T (16 keys x 64 rows) ----
    f32x4 sa[4];
#pragma unroll
    for (int nt = 0; nt < 4; ++nt) sa[nt] = (f32x4){0.f, 0.f, 0.f, 0.f};
#pragma unroll
    for (int kc = 0; kc < 4; ++kc) {
      const bf16x8 kf = ldsFrag(KbL + keyA * 128 + (((kc * 4 + quad) ^ ksw) * 8));
      sa[0] = __builtin_amdgcn_mfma_f32_16x16x32_bf16(kf, qf[0 * 4 + kc], sa[0], 0, 0, 0);
      sa[1] = __builtin_amdgcn_mfma_f32_16x16x32_bf16(kf, qf[1 * 4 + kc], sa[1], 0, 0, 0);
      sa[2] = __builtin_amdgcn_mfma_f32_16x16x32_bf16(kf, qf[2 * 4 + kc], sa[2], 0, 0, 0);
      sa[3] = __builtin_amdgcn_mfma_f32_16x16x32_bf16(kf, qf[3 * 4 + kc], sa[3], 0, 0, 0);
    }

    const float etile = SCALE * __expf(cg[goff + st * 64 + 63] - ccmax);
    const bool diag = (st == cqt);
    const int kb0 = kg * 16 + quad * 4;

    s16x4 pfr[4];
#pragma unroll
    for (int nt = 0; nt < 4; ++nt) {
      float x0 = sa[nt][0] * etile, x1 = sa[nt][1] * etile;
      float x2 = sa[nt][2] * etile, x3 = sa[nt][3] * etile;
      if (diag) {
        const int qr = nt * 16 + l16;
        if (kb0 + 0 > qr) x0 = 0.f;
        if (kb0 + 1 > qr) x1 = 0.f;
        if (kb0 + 2 > qr) x2 = 0.f;
        if (kb0 + 3 > qr) x3 = 0.f;
      }
      rsacc[nt] += (x0 + x1) + (x2 + x3);
      u32 plo, phi;
      asm("v_cvt_pk_bf16_f32 %0, %1, %2" : "=v"(plo) : "v"(x0), "v"(x1));
      asm("v_cvt_pk_bf16_f32 %0, %1, %2" : "=v"(phi) : "v"(x2), "v"(x3));
      pfr[nt] = __builtin_bit_cast(s16x4, (u32x2){plo, phi});
    }

    // ---- O^T += V^T P^T ----
#pragma unroll
    for (int mt = 0; mt < 8; ++mt) {
      const s16x4 va = *(const s16x4*)(VbL + vbase + mt * 1024);
      oa[mt][0] = mfma16x16x16bf16(va, pfr[0], oa[mt][0]);
      oa[mt][1] = mfma16x16x16bf16(va, pfr[1], oa[mt][1]);
      oa[mt][2] = mfma16x16x16bf16(va, pfr[2], oa[mt][2]);
      oa[mt][3] = mfma16x16x16bf16(va, pfr[3], oa[mt][3]);
    }
  };

  // 8-partial combine: mt-rotation rounds, all waves busy every round.
  auto epilogue = [&](int eqt, float ecmax, int dead) {
    float* osh = (float*)(SM + dead * 65536);
    float* rsh = osh + 64 * 132;
    float* ish = rsh + 512;
    // rowsum: reduce over quads (keys), publish per-wave partials
    float rst[4];
#pragma unroll
    for (int nt = 0; nt < 4; ++nt) {
      float x = rsacc[nt];
      x += __shfl_xor(x, 16, 64);
      x += __shfl_xor(x, 32, 64);
      rst[nt] = x;
    }
    if (lane < 16) {
#pragma unroll
      for (int nt = 0; nt < 4; ++nt) rsh[w * 64 + nt * 16 + lane] = rst[nt];
    }
    __syncthreads();
    if (w == 7) {
      const int row = lane;
      float tot = 0.f;
#pragma unroll
      for (int j = 0; j < 8; ++j) tot += rsh[j * 64 + row];
      const float nf = __expf(-(ecmax + fcg[goff + eqt * 64 + row]));
      ish[row] = 1.f / fmaxf(fabsf(tot), nf);
    }
    __syncthreads();
    // 8 rounds: round j, wave w accumulates vd-tile e=(w+j)&7
    for (int j = 0; j < 8; ++j) {
      const int e = (w + j) & 7;
#pragma unroll
      for (int nt = 0; nt < 4; ++nt) {
        float* ap = osh + (nt * 16 + l16) * 132 + e * 16 + quad * 4;
        f32x4 vv = oa[e][nt];
        if (j > 0) vv = vv + *(const f32x4*)ap;
        if (j == 7) vv = vv * ish[nt * 16 + l16];
        *(f32x4*)ap = vv;
      }
      __syncthreads();
    }
    // cooperative coalesced store (8 thr/row x 64B)
    const int row = tid >> 3, c0 = (tid & 7) * 16;
#pragma unroll
    for (int i = 0; i < 4; ++i) {
      const f32x4 vv = *(const f32x4*)(osh + row * 132 + c0 + i * 4);
      *(f32x4*)(out + hoff + (size_t)(eqt * 64 + row) * DHEAD + c0 + i * 4) = vv;
    }
    __syncthreads();   // osh drained before its pair is re-staged
  };

  // -------- prologue --------
  int qt = qtA, n = nA;
  float cmax = cg[goff + qtA * 64 + 63];
  loadQ(qtA);
  stage(0, 0);
  stage(1, 1);
  __syncthreads();

  // -------- 17 uniform windows (2 parallel stages each) --------
  int pr = 0;
  for (int ph = 0; ph < 2; ++ph) {
    const int c = (n + 1) >> 1;
    for (int g = 0; g < c; ++g) {
      if (g + 1 < c) {
        const int s0 = 2 * (g + 1);
        stage(s0, (pr ^ 1) * 2);
        stage((s0 + 1 < n) ? s0 + 1 : s0, (pr ^ 1) * 2 + 1);
      } else if (ph == 0) {
        stage(0, (pr ^ 1) * 2);
        stage((nB > 1) ? 1 : 0, (pr ^ 1) * 2 + 1);
      }
      const int st = 2 * g + sg;
      if (st < n) computeStage(qt, st, pr * 2 + sg, cmax);
      __syncthreads();
      pr ^= 1;
    }
    const int dead = pr ^ 1;          // pair just computed from
    if (ph == 0) loadQ(qtB);          // hide Q-load under epilogue A
    epilogue(qt, cmax, dead);
    if (ph == 0) {
      zeroAcc();
      qt = qtB; n = nB;
      cmax = cg[goff + qtB * 64 + 63];
    }
  }
}

// ---------------------------------------------------------------------------
extern "C" void kernel_launch(void* const* d_in, const int* in_sizes, int n_in,
                              void* d_out, int out_size, void* d_ws, size_t ws_size,
                              hipStream_t stream) {
  const float* q  = (const float*)d_in[0];
  const float* k  = (const float*)d_in[1];
  const float* v  = (const float*)d_in[2];
  const float* ig = (const float*)d_in[3];
  const float* fg = (const float*)d_in[4];

  const size_t gate_bytes = (size_t)3 * NBH * T_SEQ * sizeof(float);
  const size_t kv_elems   = (size_t)NBH * T_SEQ * DHEAD;
  const bool fast = ws_size >= gate_bytes + 2 * kv_elems * sizeof(u16);

  float* a_ws  = (float*)d_ws;
  float* c_ws  = a_ws + NBH * T_SEQ;
  float* fc_ws = c_ws + NBH * T_SEQ;
  u16* kbf  = (u16*)((char*)d_ws + gate_bytes);
  u16* vtbf = kbf + kv_elems;

  gate_scan_kernel<<<dim3(NBH), dim3(1024), 0, stream>>>(ig, fg, a_ws, c_ws, fc_ws);
  if (fast) {
    cvt_kv_kernel<<<dim3(T_SEQ / 64, NBH), dim3(256), 0, stream>>>(
        k, v, a_ws, c_ws, kbf, vtbf);
    mlstm_fwd_kernel<true><<<dim3(256), dim3(512), 0, stream>>>(
        q, k, v, kbf, vtbf, a_ws, c_ws, fc_ws, (float*)d_out);
  } else {
    mlstm_fwd_kernel<false><<<dim3(256), dim3(512), 0, stream>>>(
        q, k, v, kbf, vtbf, a_ws, c_ws, fc_ws, (float*)d_out);
  }
}

// Round 6
// 177.300 us; speedup vs baseline: 1.8421x; 1.8421x over previous
//
#include <hip/hip_runtime.h>

#define T_SEQ 2048
#define DHEAD 128
#define NBH 16
#define SCALE 0.08838834764831845f

typedef unsigned short u16;
typedef unsigned int u32;
typedef u16 u16x4 __attribute__((ext_vector_type(4)));
typedef u16 u16x8 __attribute__((ext_vector_type(8)));
typedef u32 u32x2 __attribute__((ext_vector_type(2)));
typedef short s16x4 __attribute__((ext_vector_type(4)));
typedef __bf16 bf16x8 __attribute__((ext_vector_type(8)));
typedef float f32x4 __attribute__((ext_vector_type(4)));

__device__ __forceinline__ u16 f2bfu(float x) {
  union { float f; unsigned u; } c; c.f = x;
  unsigned u = c.u;
  u = u + 0x7FFFu + ((u >> 16) & 1u);   // RNE
  return (u16)(u >> 16);
}

__device__ __forceinline__ bf16x8 ldsFrag(const u16* p) {
  u16x8 t = *(const u16x8*)p;
  return __builtin_bit_cast(bf16x8, t);
}

__device__ __forceinline__ f32x4 mfma16x16x16bf16(s16x4 a, s16x4 b, f32x4 c) {
#if __has_builtin(__builtin_amdgcn_mfma_f32_16x16x16bf16_1k)
  return __builtin_amdgcn_mfma_f32_16x16x16bf16_1k(a, b, c, 0, 0, 0);
#else
  asm("v_mfma_f32_16x16x16_bf16 %0, %1, %2, %0" : "+v"(c) : "v"(a), "v"(b));
  return c;
#endif
}

__device__ __forceinline__ void gld_lds16(const void* g, void* l) {
  __builtin_amdgcn_global_load_lds(
      (__attribute__((address_space(1))) const unsigned int*)g,
      (__attribute__((address_space(3))) unsigned int*)l, 16, 0, 0);
}

// ---------------------------------------------------------------------------
// Gate scan: fc=cumsum(logsigmoid(f)); a=i-fc; c=cummax(a).
// ---------------------------------------------------------------------------
__global__ __launch_bounds__(1024) void gate_scan_kernel(
    const float* __restrict__ ig, const float* __restrict__ fg,
    float* __restrict__ a_out, float* __restrict__ c_out,
    float* __restrict__ fc_out)
{
  const int bh = blockIdx.x, tid = threadIdx.x;
  const int w = tid >> 6, lane = tid & 63;
  const int base = bh * T_SEQ + tid * 2;
  __shared__ float wsum[16];
  __shared__ float wmax[16];

  const float x0 = fg[base], x1 = fg[base + 1];
  const float ls0 = fminf(x0, 0.f) - log1pf(expf(-fabsf(x0)));
  const float ls1 = fminf(x1, 0.f) - log1pf(expf(-fabsf(x1)));
  const float s = ls0 + ls1;

  float sc = s;
#pragma unroll
  for (int off = 1; off < 64; off <<= 1) {
    const float t = __shfl_up(sc, off, 64);
    if (lane >= off) sc += t;
  }
  if (lane == 63) wsum[w] = sc;
  __syncthreads();
  float wo = 0.f;
#pragma unroll
  for (int i = 0; i < 15; ++i) if (i < w) wo += wsum[i];
  const float excl = wo + (sc - s);
  const float fc0 = excl + ls0;
  const float fc1 = excl + ls0 + ls1;
  fc_out[base] = fc0; fc_out[base + 1] = fc1;
  const float a0 = ig[base] - fc0;
  const float a1 = ig[base + 1] - fc1;
  a_out[base] = a0; a_out[base + 1] = a1;

  const float m = fmaxf(a0, a1);
  float mc = m;
#pragma unroll
  for (int off = 1; off < 64; off <<= 1) {
    const float t = __shfl_up(mc, off, 64);
    if (lane >= off) mc = fmaxf(mc, t);
  }
  if (lane == 63) wmax[w] = mc;
  __syncthreads();
  float wmo = -INFINITY;
#pragma unroll
  for (int i = 0; i < 15; ++i) if (i < w) wmo = fmaxf(wmo, wmax[i]);
  const float prev = __shfl_up(mc, 1, 64);
  float exclm = (lane > 0) ? prev : -INFINITY;
  exclm = fmaxf(exclm, wmo);
  c_out[base] = fmaxf(exclm, a0);
  c_out[base + 1] = fmaxf(exclm, m);
}

// ---------------------------------------------------------------------------
// Fused pre-pass: K_hat = K*exp(a-c_end) fp32->bf16; V -> bf16 Vt transposed.
// ---------------------------------------------------------------------------
__global__ __launch_bounds__(256) void cvt_kv_kernel(
    const float* __restrict__ kk, const float* __restrict__ v,
    const float* __restrict__ ag, const float* __restrict__ cg,
    u16* __restrict__ kbf, u16* __restrict__ vt)
{
  const int bh = blockIdx.y, kt = blockIdx.x, tid = threadIdx.x;
  // ---- K part ----
  {
    const int r = tid >> 2;                 // 0..63
    const int c0 = (tid & 3) * 32;
    const int row = kt * 64 + r;
    const float sc = __expf(ag[bh * T_SEQ + row] - cg[bh * T_SEQ + (row | 63)]);
    const float* sp = kk + ((size_t)bh * T_SEQ + row) * DHEAD + c0;
    u16* dp = kbf + ((size_t)bh * T_SEQ + row) * DHEAD + c0;
#pragma unroll
    for (int j = 0; j < 8; ++j) {
      const float4 x = *(const float4*)(sp + j * 4);
      u16x4 pq;
      pq[0] = f2bfu(x.x * sc); pq[1] = f2bfu(x.y * sc);
      pq[2] = f2bfu(x.z * sc); pq[3] = f2bfu(x.w * sc);
      *(u16x4*)(dp + j * 4) = pq;
    }
  }
  // ---- V transpose part ----
  __shared__ __align__(16) u16 L[128 * 72];
  const int n0 = (tid & 31) * 4, k0 = (tid >> 5) * 8;
  const float* vp = v + ((size_t)bh * T_SEQ + kt * 64 + k0) * DHEAD + n0;
  u16 tv[4][8];
#pragma unroll
  for (int rr = 0; rr < 8; ++rr) {
    const float4 x = *(const float4*)(vp + rr * DHEAD);
    tv[0][rr] = f2bfu(x.x); tv[1][rr] = f2bfu(x.y);
    tv[2][rr] = f2bfu(x.z); tv[3][rr] = f2bfu(x.w);
  }
#pragma unroll
  for (int j = 0; j < 4; ++j) {
    u16x8 pq;
#pragma unroll
    for (int rr = 0; rr < 8; ++rr) pq[rr] = tv[j][rr];
    *(u16x8*)(&L[(n0 + j) * 72 + k0]) = pq;
  }
  __syncthreads();
  const int row = tid >> 1, s0 = (tid & 1) * 32;
  u16* op = vt + ((size_t)bh * DHEAD + row) * T_SEQ + kt * 64 + s0;
#pragma unroll
  for (int i = 0; i < 4; ++i)
    *(u16x8*)(op + i * 8) = *(const u16x8*)(&L[row * 72 + s0 + i * 8]);
}

// ---------------------------------------------------------------------------
// Main flash mLSTM.  256 blocks x 512 thr (8 waves = 2/SIMD).
// UNIFORM 17-window schedule, TWO STAGES PER WINDOW ON DIFFERENT WAVES:
//   block (bh,p): tile A=31-p (stages 0..31-p) then tile B=p (0..p);
//   ceil(nA/2)+ceil(nB/2) == 17 for every p.
// Wave = kg(4 key-groups of 16) x sg(2): wave (kg,sg) computes stage 2g+sg
// over 16 keys x ALL 64 rows -> two INDEPENDENT per-stage dep chains per
// SIMD per window.  LDS read redundancy 1x (R0's optimum).
// 4 staging slots x 32KB, pair ping-pong; epilogue overlays the dead pair.
// EPILOGUE USES ONLY COMPILE-TIME oa INDICES (rule #20: R5's runtime
// oa[(w+j)&7] sent the whole accumulator to scratch: WRITE_SIZE 16MB->1.3GB).
// ---------------------------------------------------------------------------
template <bool FAST>
__global__ __launch_bounds__(512, 1) void mlstm_fwd_kernel(
    const float* __restrict__ qg, const float* __restrict__ kxg,
    const float* __restrict__ vg,
    const u16* __restrict__ kbf, const u16* __restrict__ vtbf,
    const float* __restrict__ ag, const float* __restrict__ cg,
    const float* __restrict__ fcg, float* __restrict__ out)
{
  const int bx = (int)blockIdx.x;
  const int bh = ((bx & 7) << 1) | ((bx >> 3) & 1);   // 2 bh per XCD
  const int p  = bx >> 4;
  const int tid = (int)threadIdx.x;
  const int w = tid >> 6, lane = tid & 63;
  const int quad = lane >> 4, l16 = lane & 15;
  const int kg = w & 3, sg = w >> 2;

  const int qtA = 31 - p, qtB = p;
  const int nA = qtA + 1, nB = qtB + 1;   // nA in 17..32, nB in 1..16

  // LDS: 4 staging slots x 32KB (K 16K + V 16K each) = 128KB.
  // Epilogue osh(64x132 f32) + rsh(8x64) + ish(64) overlay the dead pair.
  __shared__ __align__(16) unsigned char SM[131072];
  u16* Kst = (u16*)SM;

  const size_t hoff = (size_t)bh * T_SEQ * DHEAD;
  const int goff = bh * T_SEQ;

  // Q -> B-frags qf[nt*4+kc]: B[k=quad*8+j][n=l16], row = qt*64+nt*16+l16
  bf16x8 qf[16];
  auto loadQ = [&](int lqt) {
    const float* qp = qg + hoff + (size_t)(lqt * 64) * DHEAD;
#pragma unroll
    for (int nt = 0; nt < 4; ++nt) {
      const float* qr = qp + (size_t)(nt * 16 + l16) * DHEAD + quad * 8;
#pragma unroll
      for (int kc = 0; kc < 4; ++kc) {
        const float4 x0 = *(const float4*)(qr + kc * 32);
        const float4 x1 = *(const float4*)(qr + kc * 32 + 4);
        u16x8 t;
        t[0] = f2bfu(x0.x); t[1] = f2bfu(x0.y); t[2] = f2bfu(x0.z); t[3] = f2bfu(x0.w);
        t[4] = f2bfu(x1.x); t[5] = f2bfu(x1.y); t[6] = f2bfu(x1.z); t[7] = f2bfu(x1.w);
        qf[nt * 4 + kc] = __builtin_bit_cast(bf16x8, t);
      }
    }
  };

  f32x4 oa[8][4];                 // O^T partial: 8 vd-tiles x 4 row-tiles
  float rsacc[4];
  auto zeroAcc = [&]() {
#pragma unroll
    for (int mt = 0; mt < 8; ++mt)
#pragma unroll
      for (int nt = 0; nt < 4; ++nt) oa[mt][nt] = (f32x4){0.f, 0.f, 0.f, 0.f};
#pragma unroll
    for (int nt = 0; nt < 4; ++nt) rsacc[nt] = 0.f;
  };
  zeroAcc();

  // ---- staging invariants: thread handles chunks B0=tid, B1=tid+512 ----
  const int B0 = tid, B1 = tid + 512;
  const int k0key = B0 >> 4, k0db = (B0 & 15) ^ (k0key & 7);
  const int k1key = B1 >> 4, k1db = (B1 & 15) ^ (k1key & 7);
  const int v0n = B0 >> 3, v0k = (B0 & 7) ^ (v0n & 7);
  const int v1n = B1 >> 3, v1k = (B1 & 7) ^ (v1n & 7);
  const u16* kG = kbf + (size_t)goff * DHEAD;
  const u16* vG = vtbf + (size_t)bh * DHEAD * T_SEQ;

  // stage key-tile st into slot (K 16KB + V 16KB); 4 gld16 per thread
  auto stage = [&](int st, int slot) {
    u16* KbL = Kst + slot * 16384;
    u16* VbL = KbL + 8192;
    if (FAST) {
      const u16* ks = kG + (size_t)st * (64 * DHEAD);
      const u16* vs = vG + st * 64;
      gld_lds16(ks + k0key * DHEAD + k0db * 8, KbL + w * 512);
      gld_lds16(ks + k1key * DHEAD + k1db * 8, KbL + 4096 + w * 512);
      gld_lds16(vs + (size_t)v0n * T_SEQ + v0k * 8, VbL + w * 512);
      gld_lds16(vs + (size_t)v1n * T_SEQ + v1k * 8, VbL + 4096 + w * 512);
    } else {
      const float ct = cg[goff + st * 64 + 63];
      const float* kp = kxg + hoff + (size_t)(st * 64) * DHEAD;
      const float* vp = vg + hoff + (size_t)(st * 64) * DHEAD;
#pragma unroll
      for (int j = 0; j < 2; ++j) {
        const int key = j ? k1key : k0key, db = j ? k1db : k0db;
        const int Bc = j ? B1 : B0;
        const float scv = __expf(ag[goff + st * 64 + key] - ct);
        const float4 x0 = *(const float4*)(kp + (size_t)key * DHEAD + db * 8);
        const float4 x1 = *(const float4*)(kp + (size_t)key * DHEAD + db * 8 + 4);
        u16x8 pk;
        pk[0] = f2bfu(x0.x * scv); pk[1] = f2bfu(x0.y * scv);
        pk[2] = f2bfu(x0.z * scv); pk[3] = f2bfu(x0.w * scv);
        pk[4] = f2bfu(x1.x * scv); pk[5] = f2bfu(x1.y * scv);
        pk[6] = f2bfu(x1.z * scv); pk[7] = f2bfu(x1.w * scv);
        *(u16x8*)(KbL + Bc * 8) = pk;
        const int n = j ? v1n : v0n, kb = j ? v1k : v0k;
        u16x8 pw;
#pragma unroll
        for (int rr = 0; rr < 8; ++rr)
          pw[rr] = f2bfu(vp[(size_t)(kb * 8 + rr) * DHEAD + n]);
        *(u16x8*)(VbL + Bc * 8) = pw;
      }
    }
  };

  const int keyA = kg * 16 + l16;         // A-frag key row (QK)
  const int ksw  = l16 & 7;
  // vd&7 == l16&7 for all mt -> V swizzle is mt-invariant:
  const int vbase = l16 * 64 + (((kg * 2 + (quad >> 1)) ^ (l16 & 7)) * 8) + (quad & 1) * 4;

  auto computeStage = [&](int cqt, int st, int slot, float ccmax) {
    const u16* KbL = Kst + slot * 16384;
    const u16* VbL = KbL + 8192;

    // ---- S^T = K_hat Q^T (16 keys x 64 rows) ----
    f32x4 sa[4];
#pragma unroll
    for (int nt = 0; nt < 4; ++nt) sa[nt] = (f32x4){0.f, 0.f, 0.f, 0.f};
#pragma unroll
    for (int kc = 0; kc < 4; ++kc) {
      const bf16x8 kf = ldsFrag(KbL + keyA * 128 + (((kc * 4 + quad) ^ ksw) * 8));
      sa[0] = __builtin_amdgcn_mfma_f32_16x16x32_bf16(kf, qf[0 * 4 + kc], sa[0], 0, 0, 0);
      sa[1] = __builtin_amdgcn_mfma_f32_16x16x32_bf16(kf, qf[1 * 4 + kc], sa[1], 0, 0, 0);
      sa[2] = __builtin_amdgcn_mfma_f32_16x16x32_bf16(kf, qf[2 * 4 + kc], sa[2], 0, 0, 0);
      sa[3] = __builtin_amdgcn_mfma_f32_16x16x32_bf16(kf, qf[3 * 4 + kc], sa[3], 0, 0, 0);
    }

    const float etile = SCALE * __expf(cg[goff + st * 64 + 63] - ccmax);
    const bool diag = (st == cqt);
    const int kb0 = kg * 16 + quad * 4;

    s16x4 pfr[4];
#pragma unroll
    for (int nt = 0; nt < 4; ++nt) {
      float x0 = sa[nt][0] * etile, x1 = sa[nt][1] * etile;
      float x2 = sa[nt][2] * etile, x3 = sa[nt][3] * etile;
      if (diag) {
        const int qr = nt * 16 + l16;
        if (kb0 + 0 > qr) x0 = 0.f;
        if (kb0 + 1 > qr) x1 = 0.f;
        if (kb0 + 2 > qr) x2 = 0.f;
        if (kb0 + 3 > qr) x3 = 0.f;
      }
      rsacc[nt] += (x0 + x1) + (x2 + x3);
      u32 plo, phi;
      asm("v_cvt_pk_bf16_f32 %0, %1, %2" : "=v"(plo) : "v"(x0), "v"(x1));
      asm("v_cvt_pk_bf16_f32 %0, %1, %2" : "=v"(phi) : "v"(x2), "v"(x3));
      pfr[nt] = __builtin_bit_cast(s16x4, (u32x2){plo, phi});
    }

    // ---- O^T += V^T P^T ----
#pragma unroll
    for (int mt = 0; mt < 8; ++mt) {
      const s16x4 va = *(const s16x4*)(VbL + vbase + mt * 1024);
      oa[mt][0] = mfma16x16x16bf16(va, pfr[0], oa[mt][0]);
      oa[mt][1] = mfma16x16x16bf16(va, pfr[1], oa[mt][1]);
      oa[mt][2] = mfma16x16x16bf16(va, pfr[2], oa[mt][2]);
      oa[mt][3] = mfma16x16x16bf16(va, pfr[3], oa[mt][3]);
    }
  };

  // 8-partial combine: serial rounds, COMPILE-TIME oa indices only.
  auto epilogue = [&](int eqt, float ecmax, int dead) {
    float* osh = (float*)(SM + dead * 65536);
    float* rsh = osh + 64 * 132;
    float* ish = rsh + 512;
    // rowsum: reduce over quads (keys), publish per-wave partials
    float rst[4];
#pragma unroll
    for (int nt = 0; nt < 4; ++nt) {
      float x = rsacc[nt];
      x += __shfl_xor(x, 16, 64);
      x += __shfl_xor(x, 32, 64);
      rst[nt] = x;
    }
    if (lane < 16) {
#pragma unroll
      for (int nt = 0; nt < 4; ++nt) rsh[w * 64 + nt * 16 + lane] = rst[nt];
    }
    __syncthreads();
    if (w == 7) {
      const int row = lane;
      float tot = 0.f;
#pragma unroll
      for (int j = 0; j < 8; ++j) tot += rsh[j * 64 + row];
      const float nf = __expf(-(ecmax + fcg[goff + eqt * 64 + row]));
      ish[row] = 1.f / fmaxf(fabsf(tot), nf);
    }
    __syncthreads();
    // 8 serial accumulate rounds; active wave uses literal oa indices
    for (int r = 0; r < 8; ++r) {
      if (w == r) {
        const float iv0 = ish[l16], iv1 = ish[16 + l16];
        const float iv2 = ish[32 + l16], iv3 = ish[48 + l16];
#pragma unroll
        for (int mt = 0; mt < 8; ++mt) {
#pragma unroll
          for (int nt = 0; nt < 4; ++nt) {
            float* ap = osh + (nt * 16 + l16) * 132 + mt * 16 + quad * 4;
            f32x4 vv = oa[mt][nt];
            if (r > 0) vv = vv + *(const f32x4*)ap;
            if (r == 7) {
              const float iv = (nt == 0) ? iv0 : (nt == 1) ? iv1 : (nt == 2) ? iv2 : iv3;
              vv = vv * iv;
            }
            *(f32x4*)ap = vv;
          }
        }
      }
      __syncthreads();
    }
    // cooperative coalesced store (8 thr/row x 64B)
    const int row = tid >> 3, c0 = (tid & 7) * 16;
#pragma unroll
    for (int i = 0; i < 4; ++i) {
      const f32x4 vv = *(const f32x4*)(osh + row * 132 + c0 + i * 4);
      *(f32x4*)(out + hoff + (size_t)(eqt * 64 + row) * DHEAD + c0 + i * 4) = vv;
    }
    __syncthreads();   // osh drained before its pair is re-staged
  };

  // -------- prologue --------
  int qt = qtA, n = nA;
  float cmax = cg[goff + qtA * 64 + 63];
  loadQ(qtA);
  stage(0, 0);
  stage(1, 1);
  __syncthreads();

  // -------- 17 uniform windows (2 parallel stages each) --------
  int pr = 0;
  for (int ph = 0; ph < 2; ++ph) {
    const int c = (n + 1) >> 1;
    for (int g = 0; g < c; ++g) {
      if (g + 1 < c) {
        const int s0 = 2 * (g + 1);
        stage(s0, (pr ^ 1) * 2);
        stage((s0 + 1 < n) ? s0 + 1 : s0, (pr ^ 1) * 2 + 1);
      } else if (ph == 0) {
        stage(0, (pr ^ 1) * 2);
        stage((nB > 1) ? 1 : 0, (pr ^ 1) * 2 + 1);
      }
      const int st = 2 * g + sg;
      if (st < n) computeStage(qt, st, pr * 2 + sg, cmax);
      __syncthreads();
      pr ^= 1;
    }
    const int dead = pr ^ 1;          // pair just computed from
    if (ph == 0) loadQ(qtB);          // hide Q-load under epilogue A
    epilogue(qt, cmax, dead);
    if (ph == 0) {
      zeroAcc();
      qt = qtB; n = nB;
      cmax = cg[goff + qtB * 64 + 63];
    }
  }
}

// ---------------------------------------------------------------------------
extern "C" void kernel_launch(void* const* d_in, const int* in_sizes, int n_in,
                              void* d_out, int out_size, void* d_ws, size_t ws_size,
                              hipStream_t stream) {
  const float* q  = (const float*)d_in[0];
  const float* k  = (const float*)d_in[1];
  const float* v  = (const float*)d_in[2];
  const float* ig = (const float*)d_in[3];
  const float* fg = (const float*)d_in[4];

  const size_t gate_bytes = (size_t)3 * NBH * T_SEQ * sizeof(float);
  const size_t kv_elems   = (size_t)NBH * T_SEQ * DHEAD;
  const bool fast = ws_size >= gate_bytes + 2 * kv_elems * sizeof(u16);

  float* a_ws  = (float*)d_ws;
  float* c_ws  = a_ws + NBH * T_SEQ;
  float* fc_ws = c_ws + NBH * T_SEQ;
  u16* kbf  = (u16*)((char*)d_ws + gate_bytes);
  u16* vtbf = kbf + kv_elems;

  gate_scan_kernel<<<dim3(NBH), dim3(1024), 0, stream>>>(ig, fg, a_ws, c_ws, fc_ws);
  if (fast) {
    cvt_kv_kernel<<<dim3(T_SEQ / 64, NBH), dim3(256), 0, stream>>>(
        k, v, a_ws, c_ws, kbf, vtbf);
    mlstm_fwd_kernel<true><<<dim3(256), dim3(512), 0, stream>>>(
        q, k, v, kbf, vtbf, a_ws, c_ws, fc_ws, (float*)d_out);
  } else {
    mlstm_fwd_kernel<false><<<dim3(256), dim3(512), 0, stream>>>(
        q, k, v, kbf, vtbf, a_ws, c_ws, fc_ws, (float*)d_out);
  }
}

// Round 7
// 162.574 us; speedup vs baseline: 2.0089x; 1.0906x over previous
//
#include <hip/hip_runtime.h>

#define T_SEQ 2048
#define DHEAD 128
#define NBH 16
#define SCALE 0.08838834764831845f

typedef unsigned short u16;
typedef unsigned int u32;
typedef u16 u16x4 __attribute__((ext_vector_type(4)));
typedef u16 u16x8 __attribute__((ext_vector_type(8)));
typedef u32 u32x2 __attribute__((ext_vector_type(2)));
typedef short s16x4 __attribute__((ext_vector_type(4)));
typedef __bf16 bf16x8 __attribute__((ext_vector_type(8)));
typedef float f32x4 __attribute__((ext_vector_type(4)));

__device__ __forceinline__ u16 f2bfu(float x) {
  union { float f; unsigned u; } c; c.f = x;
  unsigned u = c.u;
  u = u + 0x7FFFu + ((u >> 16) & 1u);   // RNE
  return (u16)(u >> 16);
}

__device__ __forceinline__ bf16x8 ldsFrag(const u16* p) {
  u16x8 t = *(const u16x8*)p;
  return __builtin_bit_cast(bf16x8, t);
}

__device__ __forceinline__ f32x4 mfma16x16x16bf16(s16x4 a, s16x4 b, f32x4 c) {
#if __has_builtin(__builtin_amdgcn_mfma_f32_16x16x16bf16_1k)
  return __builtin_amdgcn_mfma_f32_16x16x16bf16_1k(a, b, c, 0, 0, 0);
#else
  asm("v_mfma_f32_16x16x16_bf16 %0, %1, %2, %0" : "+v"(c) : "v"(a), "v"(b));
  return c;
#endif
}

__device__ __forceinline__ void gld_lds16(const void* g, void* l) {
  __builtin_amdgcn_global_load_lds(
      (__attribute__((address_space(1))) const unsigned int*)g,
      (__attribute__((address_space(3))) unsigned int*)l, 16, 0, 0);
}

// ---------------------------------------------------------------------------
// Gate scan: fc=cumsum(logsigmoid(f)); a=i-fc; c=cummax(a).
// ---------------------------------------------------------------------------
__global__ __launch_bounds__(1024) void gate_scan_kernel(
    const float* __restrict__ ig, const float* __restrict__ fg,
    float* __restrict__ a_out, float* __restrict__ c_out,
    float* __restrict__ fc_out)
{
  const int bh = blockIdx.x, tid = threadIdx.x;
  const int w = tid >> 6, lane = tid & 63;
  const int base = bh * T_SEQ + tid * 2;
  __shared__ float wsum[16];
  __shared__ float wmax[16];

  const float x0 = fg[base], x1 = fg[base + 1];
  const float ls0 = fminf(x0, 0.f) - log1pf(expf(-fabsf(x0)));
  const float ls1 = fminf(x1, 0.f) - log1pf(expf(-fabsf(x1)));
  const float s = ls0 + ls1;

  float sc = s;
#pragma unroll
  for (int off = 1; off < 64; off <<= 1) {
    const float t = __shfl_up(sc, off, 64);
    if (lane >= off) sc += t;
  }
  if (lane == 63) wsum[w] = sc;
  __syncthreads();
  float wo = 0.f;
#pragma unroll
  for (int i = 0; i < 15; ++i) if (i < w) wo += wsum[i];
  const float excl = wo + (sc - s);
  const float fc0 = excl + ls0;
  const float fc1 = excl + ls0 + ls1;
  fc_out[base] = fc0; fc_out[base + 1] = fc1;
  const float a0 = ig[base] - fc0;
  const float a1 = ig[base + 1] - fc1;
  a_out[base] = a0; a_out[base + 1] = a1;

  const float m = fmaxf(a0, a1);
  float mc = m;
#pragma unroll
  for (int off = 1; off < 64; off <<= 1) {
    const float t = __shfl_up(mc, off, 64);
    if (lane >= off) mc = fmaxf(mc, t);
  }
  if (lane == 63) wmax[w] = mc;
  __syncthreads();
  float wmo = -INFINITY;
#pragma unroll
  for (int i = 0; i < 15; ++i) if (i < w) wmo = fmaxf(wmo, wmax[i]);
  const float prev = __shfl_up(mc, 1, 64);
  float exclm = (lane > 0) ? prev : -INFINITY;
  exclm = fmaxf(exclm, wmo);
  c_out[base] = fmaxf(exclm, a0);
  c_out[base + 1] = fmaxf(exclm, m);
}

// ---------------------------------------------------------------------------
// Fused pre-pass: K_hat = K*exp(a-c_end) fp32->bf16; V -> bf16 Vt transposed.
// ---------------------------------------------------------------------------
__global__ __launch_bounds__(256) void cvt_kv_kernel(
    const float* __restrict__ kk, const float* __restrict__ v,
    const float* __restrict__ ag, const float* __restrict__ cg,
    u16* __restrict__ kbf, u16* __restrict__ vt)
{
  const int bh = blockIdx.y, kt = blockIdx.x, tid = threadIdx.x;
  // ---- K part ----
  {
    const int r = tid >> 2;                 // 0..63
    const int c0 = (tid & 3) * 32;
    const int row = kt * 64 + r;
    const float sc = __expf(ag[bh * T_SEQ + row] - cg[bh * T_SEQ + (row | 63)]);
    const float* sp = kk + ((size_t)bh * T_SEQ + row) * DHEAD + c0;
    u16* dp = kbf + ((size_t)bh * T_SEQ + row) * DHEAD + c0;
#pragma unroll
    for (int j = 0; j < 8; ++j) {
      const float4 x = *(const float4*)(sp + j * 4);
      u16x4 pq;
      pq[0] = f2bfu(x.x * sc); pq[1] = f2bfu(x.y * sc);
      pq[2] = f2bfu(x.z * sc); pq[3] = f2bfu(x.w * sc);
      *(u16x4*)(dp + j * 4) = pq;
    }
  }
  // ---- V transpose part ----
  __shared__ __align__(16) u16 L[128 * 72];
  const int n0 = (tid & 31) * 4, k0 = (tid >> 5) * 8;
  const float* vp = v + ((size_t)bh * T_SEQ + kt * 64 + k0) * DHEAD + n0;
  u16 tv[4][8];
#pragma unroll
  for (int rr = 0; rr < 8; ++rr) {
    const float4 x = *(const float4*)(vp + rr * DHEAD);
    tv[0][rr] = f2bfu(x.x); tv[1][rr] = f2bfu(x.y);
    tv[2][rr] = f2bfu(x.z); tv[3][rr] = f2bfu(x.w);
  }
#pragma unroll
  for (int j = 0; j < 4; ++j) {
    u16x8 pq;
#pragma unroll
    for (int rr = 0; rr < 8; ++rr) pq[rr] = tv[j][rr];
    *(u16x8*)(&L[(n0 + j) * 72 + k0]) = pq;
  }
  __syncthreads();
  const int row = tid >> 1, s0 = (tid & 1) * 32;
  u16* op = vt + ((size_t)bh * DHEAD + row) * T_SEQ + kt * 64 + s0;
#pragma unroll
  for (int i = 0; i < 4; ++i)
    *(u16x8*)(op + i * 8) = *(const u16x8*)(&L[row * 72 + s0 + i * 8]);
}

// ---------------------------------------------------------------------------
// Main flash mLSTM.  256 blocks x 512 thr (8 waves = 2/SIMD).
// UNIFORM 17-window schedule, TWO STAGES PER WINDOW ON DIFFERENT WAVES:
//   block (bh,p): tile A=31-p (stages 0..31-p) then tile B=p (0..p);
//   ceil(nA/2)+ceil(nB/2) == 17 for every p.
// Wave = kg(4 key-groups of 16) x sg(2): wave (kg,sg) computes stage 2g+sg
// over 16 keys x ALL 64 rows -> two INDEPENDENT per-stage dep chains per
// SIMD per window.  LDS read redundancy 1x.
// REGISTER DISCIPLINE (R5/R6 lessons):
//   - all oa indices compile-time (rule #20)
//   - loadQ(qtB) AFTER epilogue(qtA): new qf must NOT be co-live with oa
//     across the epilogue (R6: tipped past the 256-reg budget -> spill)
//   - staging B1 addresses derived from B0 + constant offset (swizzle is
//     invariant: +32 keys / +64 rows keep &7) -> fewer live address regs
// ---------------------------------------------------------------------------
template <bool FAST>
__global__ __launch_bounds__(512, 1) void mlstm_fwd_kernel(
    const float* __restrict__ qg, const float* __restrict__ kxg,
    const float* __restrict__ vg,
    const u16* __restrict__ kbf, const u16* __restrict__ vtbf,
    const float* __restrict__ ag, const float* __restrict__ cg,
    const float* __restrict__ fcg, float* __restrict__ out)
{
  const int bx = (int)blockIdx.x;
  const int bh = ((bx & 7) << 1) | ((bx >> 3) & 1);   // 2 bh per XCD
  const int p  = bx >> 4;
  const int tid = (int)threadIdx.x;
  const int w = tid >> 6, lane = tid & 63;
  const int quad = lane >> 4, l16 = lane & 15;
  const int kg = w & 3, sg = w >> 2;

  const int qtA = 31 - p, qtB = p;
  const int nA = qtA + 1, nB = qtB + 1;   // nA in 17..32, nB in 1..16

  // LDS: 4 staging slots x 32KB (K 16K + V 16K each) = 128KB.
  // Epilogue osh(64x132 f32) + rsh(8x64) + ish(64) overlay the dead pair.
  __shared__ __align__(16) unsigned char SM[131072];
  u16* Kst = (u16*)SM;

  const size_t hoff = (size_t)bh * T_SEQ * DHEAD;
  const int goff = bh * T_SEQ;

  // Q -> B-frags qf[nt*4+kc]: B[k=quad*8+j][n=l16], row = qt*64+nt*16+l16
  bf16x8 qf[16];
  auto loadQ = [&](int lqt) {
    const float* qp = qg + hoff + (size_t)(lqt * 64) * DHEAD;
#pragma unroll
    for (int nt = 0; nt < 4; ++nt) {
      const float* qr = qp + (size_t)(nt * 16 + l16) * DHEAD + quad * 8;
#pragma unroll
      for (int kc = 0; kc < 4; ++kc) {
        const float4 x0 = *(const float4*)(qr + kc * 32);
        const float4 x1 = *(const float4*)(qr + kc * 32 + 4);
        u16x8 t;
        t[0] = f2bfu(x0.x); t[1] = f2bfu(x0.y); t[2] = f2bfu(x0.z); t[3] = f2bfu(x0.w);
        t[4] = f2bfu(x1.x); t[5] = f2bfu(x1.y); t[6] = f2bfu(x1.z); t[7] = f2bfu(x1.w);
        qf[nt * 4 + kc] = __builtin_bit_cast(bf16x8, t);
      }
    }
  };

  f32x4 oa[8][4];                 // O^T partial: 8 vd-tiles x 4 row-tiles
  float rsacc[4];
  auto zeroAcc = [&]() {
#pragma unroll
    for (int mt = 0; mt < 8; ++mt)
#pragma unroll
      for (int nt = 0; nt < 4; ++nt) oa[mt][nt] = (f32x4){0.f, 0.f, 0.f, 0.f};
#pragma unroll
    for (int nt = 0; nt < 4; ++nt) rsacc[nt] = 0.f;
  };
  zeroAcc();

  // ---- staging invariants: thread handles chunks B0=tid, B1=tid+512.
  // B1 = B0 + 32 keys (K) / + 64 rows (V): &7 unchanged -> same swizzle,
  // so B1 address = B0 address + constant offset (no extra base regs).
  const int k0key = tid >> 4, k0db = (tid & 15) ^ (k0key & 7);
  const int v0n = tid >> 3, v0k = (tid & 7) ^ (v0n & 7);
  const u16* kG = kbf + (size_t)goff * DHEAD + (size_t)k0key * DHEAD + k0db * 8;
  const u16* vG = vtbf + (size_t)bh * DHEAD * T_SEQ + (size_t)v0n * T_SEQ + v0k * 8;

  // stage key-tile st into slot (K 16KB + V 16KB); 4 gld16 per thread
  auto stage = [&](int st, int slot) {
    u16* KbL = Kst + slot * 16384;
    u16* VbL = KbL + 8192;
    if (FAST) {
      const u16* ks = kG + (size_t)st * (64 * DHEAD);
      const u16* vs = vG + st * 64;
      gld_lds16(ks, KbL + w * 512);
      gld_lds16(ks + 32 * DHEAD, KbL + 4096 + w * 512);
      gld_lds16(vs, VbL + w * 512);
      gld_lds16(vs + 64 * T_SEQ, VbL + 4096 + w * 512);
    } else {
      const float ct = cg[goff + st * 64 + 63];
      const float* kp = kxg + hoff + (size_t)(st * 64 + k0key) * DHEAD + k0db * 8;
      const float* vp = vg + hoff + (size_t)(st * 64) * DHEAD;
#pragma unroll
      for (int j = 0; j < 2; ++j) {
        const int key = k0key + j * 32;
        const float scv = __expf(ag[goff + st * 64 + key] - ct);
        const float4 x0 = *(const float4*)(kp + (size_t)j * 32 * DHEAD);
        const float4 x1 = *(const float4*)(kp + (size_t)j * 32 * DHEAD + 4);
        u16x8 pk;
        pk[0] = f2bfu(x0.x * scv); pk[1] = f2bfu(x0.y * scv);
        pk[2] = f2bfu(x0.z * scv); pk[3] = f2bfu(x0.w * scv);
        pk[4] = f2bfu(x1.x * scv); pk[5] = f2bfu(x1.y * scv);
        pk[6] = f2bfu(x1.z * scv); pk[7] = f2bfu(x1.w * scv);
        *(u16x8*)(KbL + (tid + j * 512) * 8) = pk;
        const int n = v0n + j * 64;
        u16x8 pw;
#pragma unroll
        for (int rr = 0; rr < 8; ++rr)
          pw[rr] = f2bfu(vp[(size_t)(v0k * 8 + rr) * DHEAD + n]);
        *(u16x8*)(VbL + (tid + j * 512) * 8) = pw;
      }
    }
  };

  const int keyA = kg * 16 + l16;         // A-frag key row (QK)
  const int ksw  = l16 & 7;
  // vd&7 == l16&7 for all mt -> V swizzle is mt-invariant:
  const int vbase = l16 * 64 + (((kg * 2 + (quad >> 1)) ^ (l16 & 7)) * 8) + (quad & 1) * 4;

  auto computeStage = [&](int cqt, int st, int slot, float ccmax) {
    const u16* KbL = Kst + slot * 16384;
    const u16* VbL = KbL + 8192;

    // ---- S^T = K_hat Q^T (16 keys x 64 rows) ----
    f32x4 sa[4];
#pragma unroll
    for (int nt = 0; nt < 4; ++nt) sa[nt] = (f32x4){0.f, 0.f, 0.f, 0.f};
#pragma unroll
    for (int kc = 0; kc < 4; ++kc) {
      const bf16x8 kf = ldsFrag(KbL + keyA * 128 + (((kc * 4 + quad) ^ ksw) * 8));
      sa[0] = __builtin_amdgcn_mfma_f32_16x16x32_bf16(kf, qf[0 * 4 + kc], sa[0], 0, 0, 0);
      sa[1] = __builtin_amdgcn_mfma_f32_16x16x32_bf16(kf, qf[1 * 4 + kc], sa[1], 0, 0, 0);
      sa[2] = __builtin_amdgcn_mfma_f32_16x16x32_bf16(kf, qf[2 * 4 + kc], sa[2], 0, 0, 0);
      sa[3] = __builtin_amdgcn_mfma_f32_16x16x32_bf16(kf, qf[3 * 4 + kc], sa[3], 0, 0, 0);
    }

    const float etile = SCALE * __expf(cg[goff + st * 64 + 63] - ccmax);
    const bool diag = (st == cqt);
    const int kb0 = kg * 16 + quad * 4;

    s16x4 pfr[4];
#pragma unroll
    for (int nt = 0; nt < 4; ++nt) {
      float x0 = sa[nt][0] * etile, x1 = sa[nt][1] * etile;
      float x2 = sa[nt][2] * etile, x3 = sa[nt][3] * etile;
      if (diag) {
        const int qr = nt * 16 + l16;
        if (kb0 + 0 > qr) x0 = 0.f;
        if (kb0 + 1 > qr) x1 = 0.f;
        if (kb0 + 2 > qr) x2 = 0.f;
        if (kb0 + 3 > qr) x3 = 0.f;
      }
      rsacc[nt] += (x0 + x1) + (x2 + x3);
      u32 plo, phi;
      asm("v_cvt_pk_bf16_f32 %0, %1, %2" : "=v"(plo) : "v"(x0), "v"(x1));
      asm("v_cvt_pk_bf16_f32 %0, %1, %2" : "=v"(phi) : "v"(x2), "v"(x3));
      pfr[nt] = __builtin_bit_cast(s16x4, (u32x2){plo, phi});
    }

    // ---- O^T += V^T P^T ----
#pragma unroll
    for (int mt = 0; mt < 8; ++mt) {
      const s16x4 va = *(const s16x4*)(VbL + vbase + mt * 1024);
      oa[mt][0] = mfma16x16x16bf16(va, pfr[0], oa[mt][0]);
      oa[mt][1] = mfma16x16x16bf16(va, pfr[1], oa[mt][1]);
      oa[mt][2] = mfma16x16x16bf16(va, pfr[2], oa[mt][2]);
      oa[mt][3] = mfma16x16x16bf16(va, pfr[3], oa[mt][3]);
    }
  };

  // 8-partial combine: serial rounds, COMPILE-TIME oa indices only.
  auto epilogue = [&](int eqt, float ecmax, int dead) {
    float* osh = (float*)(SM + dead * 65536);
    float* rsh = osh + 64 * 132;
    float* ish = rsh + 512;
    // rowsum: reduce over quads (keys), publish per-wave partials
    float rst[4];
#pragma unroll
    for (int nt = 0; nt < 4; ++nt) {
      float x = rsacc[nt];
      x += __shfl_xor(x, 16, 64);
      x += __shfl_xor(x, 32, 64);
      rst[nt] = x;
    }
    if (lane < 16) {
#pragma unroll
      for (int nt = 0; nt < 4; ++nt) rsh[w * 64 + nt * 16 + lane] = rst[nt];
    }
    __syncthreads();
    if (w == 7) {
      const int row = lane;
      float tot = 0.f;
#pragma unroll
      for (int j = 0; j < 8; ++j) tot += rsh[j * 64 + row];
      const float nf = __expf(-(ecmax + fcg[goff + eqt * 64 + row]));
      ish[row] = 1.f / fmaxf(fabsf(tot), nf);
    }
    __syncthreads();
    // 8 serial accumulate rounds; active wave uses literal oa indices
    for (int r = 0; r < 8; ++r) {
      if (w == r) {
        const float iv0 = ish[l16], iv1 = ish[16 + l16];
        const float iv2 = ish[32 + l16], iv3 = ish[48 + l16];
#pragma unroll
        for (int mt = 0; mt < 8; ++mt) {
#pragma unroll
          for (int nt = 0; nt < 4; ++nt) {
            float* ap = osh + (nt * 16 + l16) * 132 + mt * 16 + quad * 4;
            f32x4 vv = oa[mt][nt];
            if (r > 0) vv = vv + *(const f32x4*)ap;
            if (r == 7) {
              const float iv = (nt == 0) ? iv0 : (nt == 1) ? iv1 : (nt == 2) ? iv2 : iv3;
              vv = vv * iv;
            }
            *(f32x4*)ap = vv;
          }
        }
      }
      __syncthreads();
    }
    // cooperative coalesced store (8 thr/row x 64B)
    const int row = tid >> 3, c0 = (tid & 7) * 16;
#pragma unroll
    for (int i = 0; i < 4; ++i) {
      const f32x4 vv = *(const f32x4*)(osh + row * 132 + c0 + i * 4);
      *(f32x4*)(out + hoff + (size_t)(eqt * 64 + row) * DHEAD + c0 + i * 4) = vv;
    }
    __syncthreads();   // osh drained before its pair is re-staged
  };

  // -------- prologue --------
  int qt = qtA, n = nA;
  float cmax = cg[goff + qtA * 64 + 63];
  loadQ(qtA);
  stage(0, 0);
  stage(1, 1);
  __syncthreads();

  // -------- 17 uniform windows (2 parallel stages each) --------
  int pr = 0;
  for (int ph = 0; ph < 2; ++ph) {
    const int c = (n + 1) >> 1;
    for (int g = 0; g < c; ++g) {
      if (g + 1 < c) {
        const int s0 = 2 * (g + 1);
        stage(s0, (pr ^ 1) * 2);
        stage((s0 + 1 < n) ? s0 + 1 : s0, (pr ^ 1) * 2 + 1);
      } else if (ph == 0) {
        stage(0, (pr ^ 1) * 2);
        stage((nB > 1) ? 1 : 0, (pr ^ 1) * 2 + 1);
      }
      const int st = 2 * g + sg;
      if (st < n) computeStage(qt, st, pr * 2 + sg, cmax);
      __syncthreads();
      pr ^= 1;
    }
    const int dead = pr ^ 1;          // pair just computed from
    epilogue(qt, cmax, dead);
    if (ph == 0) {
      // loadQ AFTER epilogue: qf(B) must not be co-live with oa(A) across
      // the epilogue barriers (R6 spill).  One exposed Q-load per block.
      zeroAcc();
      qt = qtB; n = nB;
      cmax = cg[goff + qtB * 64 + 63];
      loadQ(qtB);
    }
  }
}

// ---------------------------------------------------------------------------
extern "C" void kernel_launch(void* const* d_in, const int* in_sizes, int n_in,
                              void* d_out, int out_size, void* d_ws, size_t ws_size,
                              hipStream_t stream) {
  const float* q  = (const float*)d_in[0];
  const float* k  = (const float*)d_in[1];
  const float* v  = (const float*)d_in[2];
  const float* ig = (const float*)d_in[3];
  const float* fg = (const float*)d_in[4];

  const size_t gate_bytes = (size_t)3 * NBH * T_SEQ * sizeof(float);
  const size_t kv_elems   = (size_t)NBH * T_SEQ * DHEAD;
  const bool fast = ws_size >= gate_bytes + 2 * kv_elems * sizeof(u16);

  float* a_ws  = (float*)d_ws;
  float* c_ws  = a_ws + NBH * T_SEQ;
  float* fc_ws = c_ws + NBH * T_SEQ;
  u16* kbf  = (u16*)((char*)d_ws + gate_bytes);
  u16* vtbf = kbf + kv_elems;

  gate_scan_kernel<<<dim3(NBH), dim3(1024), 0, stream>>>(ig, fg, a_ws, c_ws, fc_ws);
  if (fast) {
    cvt_kv_kernel<<<dim3(T_SEQ / 64, NBH), dim3(256), 0, stream>>>(
        k, v, a_ws, c_ws, kbf, vtbf);
    mlstm_fwd_kernel<true><<<dim3(256), dim3(512), 0, stream>>>(
        q, k, v, kbf, vtbf, a_ws, c_ws, fc_ws, (float*)d_out);
  } else {
    mlstm_fwd_kernel<false><<<dim3(256), dim3(512), 0, stream>>>(
        q, k, v, kbf, vtbf, a_ws, c_ws, fc_ws, (float*)d_out);
  }
}